// Round 2
// baseline (4026.733 us; speedup 1.0000x reference)
//
#include <hip/hip_runtime.h>

typedef __bf16 bf16;
typedef __bf16 bf16x8 __attribute__((ext_vector_type(8)));
typedef float f32x4 __attribute__((ext_vector_type(4)));

#define NN 87381
#define NINT 21845
#define NLEAF 65536
#define LEAF_START 21845

__device__ __forceinline__ float sigmoidf_(float x) {
    return 1.0f / (1.0f + __expf(-x));
}
__device__ __forceinline__ float tanhf_(float x) {
    return 1.0f - 2.0f / (__expf(2.0f * x) + 1.0f);
}

// ---------------------------------------------------------------------------
// W (512 x NR fp32, row-major) -> Wt (NR x 512 bf16)
__global__ void tconv_kernel(const float* __restrict__ W, bf16* __restrict__ Wt,
                             int NR, int total) {
    int idx = blockIdx.x * 256 + threadIdx.x;
    if (idx >= total) return;
    int n = idx >> 9;
    int k = idx & 511;
    Wt[idx] = (bf16)W[(size_t)k * NR + n];
}

// W1,W2 (each 512 x NR fp32) -> Wt (NR x 1024 bf16), row n = [W1[:,n] | W2[:,n]]
__global__ void tcat_kernel(const float* __restrict__ W1, const float* __restrict__ W2,
                            bf16* __restrict__ Wt, int NR, int total) {
    int idx = blockIdx.x * 256 + threadIdx.x;
    if (idx >= total) return;
    int n = idx >> 10;
    int kk = idx & 1023;
    const float* src = (kk < 512) ? W1 : W2;
    int k = kk & 511;
    Wt[idx] = (bf16)src[(size_t)k * NR + n];
}

// ---------------------------------------------------------------------------
// C[M x N] = Acat[M x K] @ Bt[N x K]^T + bias1 + bias2  (K = ksegs*512)
//   A seg0 = A1 (fp32 or bf16; row index gr>>a1shift), A seg1 = A2 (bf16).
//   Bt rows have leading dim bstride. Output fp32 (Cf) or bf16 (Cb).
// Tile 128x128, BK=64, 4 waves (2x2), each wave 64x64 via 4x4 of 16x16x32 MFMA.
#define GLDK 72   // 64 + 8 pad; row stride 144 B = 9*16 B (keeps 16B alignment)

__global__ __launch_bounds__(256)
void gemm_frag_kernel(const void* __restrict__ A1_, int a1fp32, int a1shift,
                      const bf16* __restrict__ A2,
                      const bf16* __restrict__ Bt, int bstride, int ksegs,
                      float* __restrict__ Cf, bf16* __restrict__ Cb,
                      const float* __restrict__ bias1, const float* __restrict__ bias2,
                      int M, int N, int relu)
{
    __shared__ __align__(16) bf16 As[128 * GLDK];
    __shared__ __align__(16) bf16 Bs[128 * GLDK];
    const int tid  = threadIdx.x;
    const int wave = tid >> 6;
    const int lane = tid & 63;
    const int bm = blockIdx.x * 128;
    const int bn = blockIdx.y * 128;
    const int wm = (wave & 1) * 64;
    const int wn = (wave >> 1) * 64;
    const int lm   = lane & 15;
    const int quad = lane >> 4;

    f32x4 acc[4][4];
#pragma unroll
    for (int i = 0; i < 4; ++i)
#pragma unroll
        for (int j = 0; j < 4; ++j) acc[i][j] = (f32x4){0.f, 0.f, 0.f, 0.f};

    const int K = ksegs << 9;
    for (int k0 = 0; k0 < K; k0 += 64) {
        const int seg   = k0 >> 9;
        const int kseg0 = k0 & 511;
        // stage A tile: 128 rows x 64 k = 1024 16B-chunks; 4 per thread
#pragma unroll
        for (int i = 0; i < 4; ++i) {
            int c  = tid + 256 * i;
            int r  = c >> 3;
            int kc = (c & 7) << 3;
            int gr = bm + r; gr = (gr < M) ? gr : (M - 1);
            bf16x8 v;
            if (seg == 0) {
                int ar = gr >> a1shift;
                if (a1fp32) {
                    const float* Af = (const float*)A1_;
                    const float4 f0 = *reinterpret_cast<const float4*>(Af + (size_t)ar * 512 + kseg0 + kc);
                    const float4 f1 = *reinterpret_cast<const float4*>(Af + (size_t)ar * 512 + kseg0 + kc + 4);
                    v[0] = (bf16)f0.x; v[1] = (bf16)f0.y; v[2] = (bf16)f0.z; v[3] = (bf16)f0.w;
                    v[4] = (bf16)f1.x; v[5] = (bf16)f1.y; v[6] = (bf16)f1.z; v[7] = (bf16)f1.w;
                } else {
                    const bf16* Ab = (const bf16*)A1_;
                    v = *reinterpret_cast<const bf16x8*>(Ab + (size_t)ar * 512 + kseg0 + kc);
                }
            } else {
                v = *reinterpret_cast<const bf16x8*>(A2 + (size_t)gr * 512 + kseg0 + kc);
            }
            *reinterpret_cast<bf16x8*>(&As[r * GLDK + kc]) = v;
        }
        // stage B tile
#pragma unroll
        for (int i = 0; i < 4; ++i) {
            int c  = tid + 256 * i;
            int r  = c >> 3;
            int kc = (c & 7) << 3;
            const bf16x8 v = *reinterpret_cast<const bf16x8*>(
                Bt + (size_t)(bn + r) * bstride + k0 + kc);
            *reinterpret_cast<bf16x8*>(&Bs[r * GLDK + kc]) = v;
        }
        __syncthreads();
#pragma unroll
        for (int kk = 0; kk < 64; kk += 32) {
            bf16x8 areg[4], breg[4];
#pragma unroll
            for (int mi = 0; mi < 4; ++mi)
                areg[mi] = *reinterpret_cast<const bf16x8*>(
                    &As[(wm + mi * 16 + lm) * GLDK + kk + quad * 8]);
#pragma unroll
            for (int ni = 0; ni < 4; ++ni)
                breg[ni] = *reinterpret_cast<const bf16x8*>(
                    &Bs[(wn + ni * 16 + lm) * GLDK + kk + quad * 8]);
#pragma unroll
            for (int mi = 0; mi < 4; ++mi)
#pragma unroll
                for (int ni = 0; ni < 4; ++ni)
                    acc[mi][ni] = __builtin_amdgcn_mfma_f32_16x16x32_bf16(
                        areg[mi], breg[ni], acc[mi][ni], 0, 0, 0);
        }
        __syncthreads();
    }

    // epilogue: C/D layout row=(lane>>4)*4+reg, col=lane&15 (m89-verified)
#pragma unroll
    for (int ni = 0; ni < 4; ++ni) {
        int col = bn + wn + ni * 16 + lm;
        float bsum = (bias1 ? bias1[col] : 0.f) + (bias2 ? bias2[col] : 0.f);
#pragma unroll
        for (int mi = 0; mi < 4; ++mi) {
#pragma unroll
            for (int r = 0; r < 4; ++r) {
                int row = bm + wm + mi * 16 + quad * 4 + r;
                if (row < M) {
                    float v = acc[mi][ni][r] + bsum;
                    if (relu) v = (v > 0.f) ? v : 0.f;
                    if (Cf) Cf[(size_t)row * N + col] = v;
                    else    Cb[(size_t)row * N + col] = (bf16)v;
                }
            }
        }
    }
}

// ---------------------------------------------------------------------------
// Leaf elementwise: IOU holds full preactivation (both biases). Local rows.
__global__ void leaf_ew_kernel(const bf16* __restrict__ IOU, bf16* __restrict__ h_out,
                               float* __restrict__ cell_out, int total)
{
    int idx = blockIdx.x * 256 + threadIdx.x;
    if (idx >= total) return;
    int m = idx >> 9;
    size_t r3 = (size_t)m * 1536 + (idx & 511);
    float i_ = sigmoidf_((float)IOU[r3]);
    float o_ = sigmoidf_((float)IOU[r3 + 512]);
    float u_ = tanhf_((float)IOU[r3 + 1024]);
    float c = i_ * u_;
    cell_out[idx] = c;
    h_out[idx]    = (bf16)(o_ * tanhf_(c));
}

// Internal-node elementwise: IOU (E x 1536, full preact), CF (4E x 512, full preact),
// cellc (4E x 512 fp32, chunk-local child rows).
__global__ void internal_ew_kernel(const bf16* __restrict__ IOU, const bf16* __restrict__ CF,
                                   const float* __restrict__ cellc, bf16* __restrict__ h_out,
                                   float* __restrict__ cell_out, int total)
{
    int idx = blockIdx.x * 256 + threadIdx.x;
    if (idx >= total) return;
    int m = idx >> 9;
    int j = idx & 511;
    size_t r3 = (size_t)m * 1536 + j;
    float i_ = sigmoidf_((float)IOU[r3]);
    float o_ = sigmoidf_((float)IOU[r3 + 512]);
    float u_ = tanhf_((float)IOU[r3 + 1024]);
    float acc = 0.f;
#pragma unroll
    for (int k = 0; k < 4; ++k) {
        size_t cidx = (size_t)(4 * m + k) * 512 + j;
        float f = sigmoidf_((float)CF[cidx]);
        acc += f * cellc[cidx];
    }
    float c = i_ * u_ + acc;
    cell_out[idx] = c;
    h_out[idx]    = (bf16)(o_ * tanhf_(c));
}

// Children hidden sum (4 consecutive rows) -> bf16
__global__ void hs_kernel(const bf16* __restrict__ hc, bf16* __restrict__ HS, int total)
{
    int idx = blockIdx.x * 256 + threadIdx.x;
    if (idx >= total) return;
    int m = idx >> 9;
    int j = idx & 511;
    float s = 0.f;
#pragma unroll
    for (int k = 0; k < 4; ++k) s += (float)hc[(size_t)(4 * m + k) * 512 + j];
    HS[idx] = (bf16)s;
}

// tree_emb = column sum of node_emb (two-pass, deterministic)
__global__ void reduce_partial_kernel(const float* __restrict__ ne, float* __restrict__ partial, int Nn)
{
    int c = threadIdx.x;
    int b = blockIdx.x;
    float acc = 0.f;
    for (int r = b; r < Nn; r += 256) acc += ne[(size_t)r * 256 + c];
    partial[b * 256 + c] = acc;
}
__global__ void reduce_final_kernel(const float* __restrict__ partial, float* __restrict__ tree)
{
    int c = threadIdx.x;
    float acc = 0.f;
    for (int b = 0; b < 256; ++b) acc += partial[b * 256 + c];
    tree[c] = acc;
}

// ---------------------------------------------------------------------------
extern "C" void kernel_launch(void* const* d_in, const int* in_sizes, int n_in,
                              void* d_out, int out_size, void* d_ws, size_t ws_size,
                              hipStream_t stream)
{
    const float* x      = (const float*)d_in[0];
    const float* W_in   = (const float*)d_in[8];
    const float* b_in   = (const float*)d_in[9];
    const float* W_ioux = (const float*)d_in[10];
    const float* b_ioux = (const float*)d_in[11];
    const float* W_iouh = (const float*)d_in[12];
    const float* b_iouh = (const float*)d_in[13];
    const float* W_fx   = (const float*)d_in[14];
    const float* b_fx   = (const float*)d_in[15];
    const float* W_fh   = (const float*)d_in[16];
    const float* b_fh   = (const float*)d_in[17];
    const float* W_out  = (const float*)d_in[18];
    const float* b_out  = (const float*)d_in[19];

    static const int LS[10] = {0, 1, 5, 21, 85, 341, 1365, 5461, 21845, 87381};

    char* ws = (char*)d_ws;
    size_t off = 0;
    auto take = [&](size_t bytes) -> void* {
        void* p = ws + off;
        off += (bytes + 255) & ~(size_t)255;
        return p;
    };
    // total ~207 MB
    bf16*  wt_in      = (bf16*) take((size_t)512 * 512 * 2);
    bf16*  wt_out     = (bf16*) take((size_t)256 * 512 * 2);
    bf16*  wt_iou_cat = (bf16*) take((size_t)2 * 1536 * 1024 * 2);
    bf16*  wt_f_cat   = (bf16*) take((size_t)2 * 512 * 1024 * 2);
    bf16*  h          = (bf16*) take((size_t)NN * 512 * 2);
    float* cell_int   = (float*)take((size_t)NINT * 512 * 4);
    float* cell_leaf  = (float*)take((size_t)8192 * 512 * 4);
    bf16*  IOU        = (bf16*) take((size_t)8192 * 1536 * 2);
    bf16*  CF         = (bf16*) take((size_t)16384 * 512 * 2);
    bf16*  HS         = (bf16*) take((size_t)4096 * 512 * 2);
    float* partial    = (float*)take((size_t)256 * 256 * 4);

    dim3 blk(256);
    auto tgrid = [](int total) { return dim3((unsigned)((total + 255) / 256)); };

    // --- weight transpose+convert (~9 MB, one pass) ---
    tconv_kernel<<<tgrid(512 * 512), blk, 0, stream>>>(W_in, wt_in, 512, 512 * 512);
    tconv_kernel<<<tgrid(256 * 512), blk, 0, stream>>>(W_out, wt_out, 256, 256 * 512);
    for (int l = 0; l < 2; ++l) {
        tcat_kernel<<<tgrid(1536 * 1024), blk, 0, stream>>>(
            W_ioux + (size_t)l * 512 * 1536, W_iouh + (size_t)l * 512 * 1536,
            wt_iou_cat + (size_t)l * 1536 * 1024, 1536, 1536 * 1024);
        tcat_kernel<<<tgrid(512 * 1024), blk, 0, stream>>>(
            W_fx + (size_t)l * 512 * 512, W_fh + (size_t)l * 512 * 512,
            wt_f_cat + (size_t)l * 512 * 1024, 512, 512 * 1024);
    }

    auto gemm = [&](const void* A1, int a1fp32, int a1shift, const bf16* A2,
                    const bf16* Bt, int bstride, int ksegs,
                    float* Cf, bf16* Cb, const float* b1, const float* b2,
                    int M, int N, int relu) {
        dim3 grid((unsigned)((M + 127) / 128), (unsigned)(N / 128));
        gemm_frag_kernel<<<grid, blk, 0, stream>>>(A1, a1fp32, a1shift, A2, Bt, bstride,
                                                   ksegs, Cf, Cb, b1, b2, M, N, relu);
    };

    // --- input projection: h = relu(x @ W_in + b_in) (fp32 A converted in staging) ---
    gemm(x, 1, 0, nullptr, wt_in, 512, 1, nullptr, h, b_in, nullptr, NN, 512, 1);

    for (int l = 0; l < 2; ++l) {
        const bf16* wiou = wt_iou_cat + (size_t)l * 1536 * 1024;
        const bf16* wf   = wt_f_cat + (size_t)l * 512 * 1024;
        const float* bx1 = b_ioux + (size_t)l * 1536;
        const float* bx2 = b_iouh + (size_t)l * 1536;
        const float* bf1 = b_fx + (size_t)l * 512;
        const float* bf2 = b_fh + (size_t)l * 512;

        // leaves + level-7 parents, pipelined in 8 chunks
        for (int c = 0; c < 8; ++c) {
            int lr0 = LEAF_START + 8192 * c;   // leaf rows [lr0, lr0+8192)
            // leaf iou: only W_ioux half of wiou (ksegs=1, bstride=1024)
            gemm(h + (size_t)lr0 * 512, 0, 0, nullptr, wiou, 1024, 1,
                 nullptr, IOU, bx1, bx2, 8192, 1536, 0);
            leaf_ew_kernel<<<tgrid(8192 * 512), blk, 0, stream>>>(
                IOU, h + (size_t)lr0 * 512, cell_leaf, 8192 * 512);
            int p0  = 5461 + 2048 * c;         // level-7 parents
            int cs0 = 4 * p0 + 1;              // == lr0
            hs_kernel<<<tgrid(2048 * 512), blk, 0, stream>>>(
                h + (size_t)cs0 * 512, HS, 2048 * 512);
            gemm(h + (size_t)p0 * 512, 0, 0, HS, wiou, 1024, 2,
                 nullptr, IOU, bx1, bx2, 2048, 1536, 0);
            gemm(h + (size_t)p0 * 512, 0, 2, h + (size_t)cs0 * 512, wf, 1024, 2,
                 nullptr, CF, bf1, bf2, 4 * 2048, 512, 0);
            internal_ew_kernel<<<tgrid(2048 * 512), blk, 0, stream>>>(
                IOU, CF, cell_leaf, h + (size_t)p0 * 512,
                cell_int + (size_t)p0 * 512, 2048 * 512);
        }
        // levels 6..0
        for (int d = 6; d >= 0; --d) {
            int s  = LS[d];
            int E  = LS[d + 1] - LS[d];
            int cs = 4 * s + 1;                // == LS[d+1]
            hs_kernel<<<tgrid(E * 512), blk, 0, stream>>>(
                h + (size_t)cs * 512, HS, E * 512);
            gemm(h + (size_t)s * 512, 0, 0, HS, wiou, 1024, 2,
                 nullptr, IOU, bx1, bx2, E, 1536, 0);
            gemm(h + (size_t)s * 512, 0, 2, h + (size_t)cs * 512, wf, 1024, 2,
                 nullptr, CF, bf1, bf2, 4 * E, 512, 0);
            internal_ew_kernel<<<tgrid(E * 512), blk, 0, stream>>>(
                IOU, CF, cell_int + (size_t)cs * 512, h + (size_t)s * 512,
                cell_int + (size_t)s * 512, E * 512);
        }
    }

    // --- output projection + tree reduction ---
    float* node_emb = (float*)d_out;
    gemm(h, 0, 0, nullptr, wt_out, 512, 1, node_emb, nullptr, b_out, nullptr, NN, 256, 0);
    reduce_partial_kernel<<<dim3(256), blk, 0, stream>>>(node_emb, partial, NN);
    reduce_final_kernel<<<dim3(1), blk, 0, stream>>>(partial, node_emb + (size_t)NN * 256);
}

// Round 3
// 3134.553 us; speedup vs baseline: 1.2846x; 1.2846x over previous
//
#include <hip/hip_runtime.h>

typedef __bf16 bf16;
typedef __bf16 bf16x8 __attribute__((ext_vector_type(8)));
typedef float f32x4 __attribute__((ext_vector_type(4)));

#define NN 87381
#define NINT 21845
#define NLEAF 65536
#define LEAF_START 21845

__device__ __forceinline__ float sigmoidf_(float x) {
    return 1.0f / (1.0f + __expf(-x));
}
__device__ __forceinline__ float tanhf_(float x) {
    return 1.0f - 2.0f / (__expf(2.0f * x) + 1.0f);
}

// async 16B global -> LDS (lane-contiguous dest required)
__device__ __forceinline__ void gload_lds16(const bf16* g, bf16* l) {
    __builtin_amdgcn_global_load_lds(
        (const __attribute__((address_space(1))) unsigned int*)g,
        (__attribute__((address_space(3))) unsigned int*)l, 16, 0, 0);
}

// ---------------------------------------------------------------------------
// W (512 x NR fp32, row-major) -> Wt (NR x 512 bf16)
__global__ void tconv_kernel(const float* __restrict__ W, bf16* __restrict__ Wt,
                             int NR, int total) {
    int idx = blockIdx.x * 256 + threadIdx.x;
    if (idx >= total) return;
    int n = idx >> 9;
    int k = idx & 511;
    Wt[idx] = (bf16)W[(size_t)k * NR + n];
}

// W1,W2 (each 512 x NR fp32) -> Wt (NR x 1024 bf16), row n = [W1[:,n] | W2[:,n]]
__global__ void tcat_kernel(const float* __restrict__ W1, const float* __restrict__ W2,
                            bf16* __restrict__ Wt, int NR, int total) {
    int idx = blockIdx.x * 256 + threadIdx.x;
    if (idx >= total) return;
    int n = idx >> 10;
    int kk = idx & 1023;
    const float* src = (kk < 512) ? W1 : W2;
    int k = kk & 511;
    Wt[idx] = (bf16)src[(size_t)k * NR + n];
}

// x fp32 -> bf16, vectorized (4 floats / thread)
__global__ void convx_kernel(const float* __restrict__ X, bf16* __restrict__ Y, int total4) {
    int idx = blockIdx.x * 256 + threadIdx.x;
    if (idx >= total4) return;
    const float4 f = *reinterpret_cast<const float4*>(X + (size_t)idx * 4);
    bf16 o[4] = {(bf16)f.x, (bf16)f.y, (bf16)f.z, (bf16)f.w};
    *reinterpret_cast<ushort2*>(Y + (size_t)idx * 4 + 0) = *reinterpret_cast<ushort2*>(&o[0]);
    *reinterpret_cast<ushort2*>(Y + (size_t)idx * 4 + 2) = *reinterpret_cast<ushort2*>(&o[2]);
}

// ---------------------------------------------------------------------------
// C[M x N] = Acat[M x K] @ Bt[N x K]^T + bias1 + bias2  (K = ksegs*512)
//   A seg0 = A1 (bf16; row index gr>>a1shift), A seg1 = A2 (bf16).
//   Bt rows have leading dim bstride. Output fp32 (Cf) or bf16 (Cb).
// Tile 128x128, BK=64, 4 waves (2x2), each wave 64x64 via 4x4 of 16x16x32 MFMA.
// Staging via global_load_lds width=16 into UNPADDED 128x64 LDS (m97 structure).
__global__ __launch_bounds__(256)
void gemm_frag_kernel(const bf16* __restrict__ A1, int a1shift,
                      const bf16* __restrict__ A2,
                      const bf16* __restrict__ Bt, int bstride, int ksegs,
                      float* __restrict__ Cf, bf16* __restrict__ Cb,
                      const float* __restrict__ bias1, const float* __restrict__ bias2,
                      int M, int N, int relu)
{
    __shared__ __align__(16) bf16 As[128 * 64];
    __shared__ __align__(16) bf16 Bs[128 * 64];
    const int tid  = threadIdx.x;
    const int wave = tid >> 6;
    const int lane = tid & 63;
    const int bm = blockIdx.x * 128;
    const int bn = blockIdx.y * 128;
    const int wm = (wave & 1) * 64;
    const int wn = (wave >> 1) * 64;
    const int lm   = lane & 15;
    const int quad = lane >> 4;

    f32x4 acc[4][4];
#pragma unroll
    for (int i = 0; i < 4; ++i)
#pragma unroll
        for (int j = 0; j < 4; ++j) acc[i][j] = (f32x4){0.f, 0.f, 0.f, 0.f};

    const int K = ksegs << 9;
    for (int k0 = 0; k0 < K; k0 += 64) {
        const int seg   = k0 >> 9;
        const int kseg0 = k0 & 511;
        const bf16* __restrict__ Asrc = (seg == 0) ? A1 : A2;
        const int shift = (seg == 0) ? a1shift : 0;
        // stage A tile: 128 rows x 64 k = 1024 16B-chunks; 4 per thread.
        // LDS offset = chunk*16B == wave-uniform base + lane*16 (global_load_lds reqt)
#pragma unroll
        for (int i = 0; i < 4; ++i) {
            int c  = i * 256 + tid;
            int r  = c >> 3;
            int kc = (c & 7) << 3;
            int gr = bm + r; gr = (gr < M) ? gr : (M - 1);
            gload_lds16(Asrc + ((size_t)(gr >> shift) << 9) + kseg0 + kc, &As[c << 3]);
        }
        // stage B tile
#pragma unroll
        for (int i = 0; i < 4; ++i) {
            int c  = i * 256 + tid;
            int r  = c >> 3;
            int kc = (c & 7) << 3;
            gload_lds16(Bt + (size_t)(bn + r) * bstride + k0 + kc, &Bs[c << 3]);
        }
        __syncthreads();
#pragma unroll
        for (int kk = 0; kk < 64; kk += 32) {
            bf16x8 areg[4], breg[4];
#pragma unroll
            for (int mi = 0; mi < 4; ++mi)
                areg[mi] = *reinterpret_cast<const bf16x8*>(
                    &As[(wm + mi * 16 + lm) * 64 + kk + quad * 8]);
#pragma unroll
            for (int ni = 0; ni < 4; ++ni)
                breg[ni] = *reinterpret_cast<const bf16x8*>(
                    &Bs[(wn + ni * 16 + lm) * 64 + kk + quad * 8]);
#pragma unroll
            for (int mi = 0; mi < 4; ++mi)
#pragma unroll
                for (int ni = 0; ni < 4; ++ni)
                    acc[mi][ni] = __builtin_amdgcn_mfma_f32_16x16x32_bf16(
                        areg[mi], breg[ni], acc[mi][ni], 0, 0, 0);
        }
        __syncthreads();
    }

    // epilogue: C/D layout row=(lane>>4)*4+reg, col=lane&15 (m89-verified)
#pragma unroll
    for (int ni = 0; ni < 4; ++ni) {
        int col = bn + wn + ni * 16 + lm;
        float bsum = (bias1 ? bias1[col] : 0.f) + (bias2 ? bias2[col] : 0.f);
#pragma unroll
        for (int mi = 0; mi < 4; ++mi) {
#pragma unroll
            for (int r = 0; r < 4; ++r) {
                int row = bm + wm + mi * 16 + quad * 4 + r;
                if (row < M) {
                    float v = acc[mi][ni][r] + bsum;
                    if (relu) v = (v > 0.f) ? v : 0.f;
                    if (Cf) Cf[(size_t)row * N + col] = v;
                    else    Cb[(size_t)row * N + col] = (bf16)v;
                }
            }
        }
    }
}

// ---------------------------------------------------------------------------
// Leaf elementwise (x8 vectorized): IOU full preact -> h, cell.
__global__ void leaf_ew_kernel(const bf16* __restrict__ IOU, bf16* __restrict__ h_out,
                               float* __restrict__ cell_out, int total8)
{
    int idx = blockIdx.x * 256 + threadIdx.x;
    if (idx >= total8) return;
    int m  = idx >> 6;
    int j0 = (idx & 63) << 3;
    size_t r3 = (size_t)m * 1536 + j0;
    const bf16x8 iv = *reinterpret_cast<const bf16x8*>(&IOU[r3]);
    const bf16x8 ov = *reinterpret_cast<const bf16x8*>(&IOU[r3 + 512]);
    const bf16x8 uv = *reinterpret_cast<const bf16x8*>(&IOU[r3 + 1024]);
    bf16x8 hv;
    float cv[8];
#pragma unroll
    for (int t = 0; t < 8; ++t) {
        float i_ = sigmoidf_((float)iv[t]);
        float o_ = sigmoidf_((float)ov[t]);
        float u_ = tanhf_((float)uv[t]);
        float c = i_ * u_;
        cv[t] = c;
        hv[t] = (bf16)(o_ * tanhf_(c));
    }
    *reinterpret_cast<bf16x8*>(&h_out[(size_t)idx * 8]) = hv;
    *reinterpret_cast<float4*>(&cell_out[(size_t)idx * 8])     = *reinterpret_cast<float4*>(&cv[0]);
    *reinterpret_cast<float4*>(&cell_out[(size_t)idx * 8 + 4]) = *reinterpret_cast<float4*>(&cv[4]);
}

// Internal-node elementwise (x8): IOU (E x 1536), CF (4E x 512), cellc (4E x 512 fp32).
__global__ void internal_ew_kernel(const bf16* __restrict__ IOU, const bf16* __restrict__ CF,
                                   const float* __restrict__ cellc, bf16* __restrict__ h_out,
                                   float* __restrict__ cell_out, int total8)
{
    int idx = blockIdx.x * 256 + threadIdx.x;
    if (idx >= total8) return;
    int m  = idx >> 6;
    int j0 = (idx & 63) << 3;
    size_t r3 = (size_t)m * 1536 + j0;
    const bf16x8 iv = *reinterpret_cast<const bf16x8*>(&IOU[r3]);
    const bf16x8 ov = *reinterpret_cast<const bf16x8*>(&IOU[r3 + 512]);
    const bf16x8 uv = *reinterpret_cast<const bf16x8*>(&IOU[r3 + 1024]);
    float accv[8];
#pragma unroll
    for (int t = 0; t < 8; ++t) accv[t] = 0.f;
#pragma unroll
    for (int k = 0; k < 4; ++k) {
        size_t cr = (size_t)(4 * m + k) * 512 + j0;
        const bf16x8 fv = *reinterpret_cast<const bf16x8*>(&CF[cr]);
        const float4 c0 = *reinterpret_cast<const float4*>(&cellc[cr]);
        const float4 c1 = *reinterpret_cast<const float4*>(&cellc[cr + 4]);
        const float cc[8] = {c0.x, c0.y, c0.z, c0.w, c1.x, c1.y, c1.z, c1.w};
#pragma unroll
        for (int t = 0; t < 8; ++t) accv[t] += sigmoidf_((float)fv[t]) * cc[t];
    }
    bf16x8 hv;
    float cv[8];
#pragma unroll
    for (int t = 0; t < 8; ++t) {
        float i_ = sigmoidf_((float)iv[t]);
        float o_ = sigmoidf_((float)ov[t]);
        float u_ = tanhf_((float)uv[t]);
        float c = i_ * u_ + accv[t];
        cv[t] = c;
        hv[t] = (bf16)(o_ * tanhf_(c));
    }
    *reinterpret_cast<bf16x8*>(&h_out[(size_t)idx * 8]) = hv;
    *reinterpret_cast<float4*>(&cell_out[(size_t)idx * 8])     = *reinterpret_cast<float4*>(&cv[0]);
    *reinterpret_cast<float4*>(&cell_out[(size_t)idx * 8 + 4]) = *reinterpret_cast<float4*>(&cv[4]);
}

// Children hidden sum (4 consecutive rows) -> bf16, x8 vectorized
__global__ void hs_kernel(const bf16* __restrict__ hc, bf16* __restrict__ HS, int total8)
{
    int idx = blockIdx.x * 256 + threadIdx.x;
    if (idx >= total8) return;
    int m  = idx >> 6;
    int j0 = (idx & 63) << 3;
    float s[8];
#pragma unroll
    for (int t = 0; t < 8; ++t) s[t] = 0.f;
#pragma unroll
    for (int k = 0; k < 4; ++k) {
        const bf16x8 v = *reinterpret_cast<const bf16x8*>(&hc[(size_t)(4 * m + k) * 512 + j0]);
#pragma unroll
        for (int t = 0; t < 8; ++t) s[t] += (float)v[t];
    }
    bf16x8 o;
#pragma unroll
    for (int t = 0; t < 8; ++t) o[t] = (bf16)s[t];
    *reinterpret_cast<bf16x8*>(&HS[(size_t)idx * 8]) = o;
}

// tree_emb = column sum of node_emb (two-pass, deterministic)
__global__ void reduce_partial_kernel(const float* __restrict__ ne, float* __restrict__ partial, int Nn)
{
    int c = threadIdx.x;
    int b = blockIdx.x;
    float acc = 0.f;
    for (int r = b; r < Nn; r += 256) acc += ne[(size_t)r * 256 + c];
    partial[b * 256 + c] = acc;
}
__global__ void reduce_final_kernel(const float* __restrict__ partial, float* __restrict__ tree)
{
    int c = threadIdx.x;
    float acc = 0.f;
    for (int b = 0; b < 256; ++b) acc += partial[b * 256 + c];
    tree[c] = acc;
}

// ---------------------------------------------------------------------------
extern "C" void kernel_launch(void* const* d_in, const int* in_sizes, int n_in,
                              void* d_out, int out_size, void* d_ws, size_t ws_size,
                              hipStream_t stream)
{
    const float* x      = (const float*)d_in[0];
    const float* W_in   = (const float*)d_in[8];
    const float* b_in   = (const float*)d_in[9];
    const float* W_ioux = (const float*)d_in[10];
    const float* b_ioux = (const float*)d_in[11];
    const float* W_iouh = (const float*)d_in[12];
    const float* b_iouh = (const float*)d_in[13];
    const float* W_fx   = (const float*)d_in[14];
    const float* b_fx   = (const float*)d_in[15];
    const float* W_fh   = (const float*)d_in[16];
    const float* b_fh   = (const float*)d_in[17];
    const float* W_out  = (const float*)d_in[18];
    const float* b_out  = (const float*)d_in[19];

    static const int LS[10] = {0, 1, 5, 21, 85, 341, 1365, 5461, 21845, 87381};

    char* ws = (char*)d_ws;
    size_t off = 0;
    auto take = [&](size_t bytes) -> void* {
        void* p = ws + off;
        off += (bytes + 255) & ~(size_t)255;
        return p;
    };
    // total ~207 MB
    bf16*  wt_in      = (bf16*) take((size_t)512 * 512 * 2);
    bf16*  wt_out     = (bf16*) take((size_t)256 * 512 * 2);
    bf16*  wt_iou_cat = (bf16*) take((size_t)2 * 1536 * 1024 * 2);
    bf16*  wt_f_cat   = (bf16*) take((size_t)2 * 512 * 1024 * 2);
    bf16*  h          = (bf16*) take((size_t)NN * 512 * 2);
    float* cell_int   = (float*)take((size_t)NINT * 512 * 4);
    float* cell_leaf  = (float*)take((size_t)8192 * 512 * 4);
    bf16*  IOU        = (bf16*) take((size_t)8192 * 1536 * 2);
    bf16*  CF         = (bf16*) take((size_t)16384 * 512 * 2);
    bf16*  HS         = (bf16*) take((size_t)4096 * 512 * 2);
    float* partial    = (float*)take((size_t)256 * 256 * 4);
    // x-as-bf16 staging: aliases cell/IOU region (dead until first internal level)
    bf16*  xbf        = (bf16*)cell_int;   // needs NN*512*2 = 89.5 MB < 108 MB region

    dim3 blk(256);
    auto tgrid = [](int total) { return dim3((unsigned)((total + 255) / 256)); };

    // --- weight transpose+convert (~9 MB, one pass) ---
    tconv_kernel<<<tgrid(512 * 512), blk, 0, stream>>>(W_in, wt_in, 512, 512 * 512);
    tconv_kernel<<<tgrid(256 * 512), blk, 0, stream>>>(W_out, wt_out, 256, 256 * 512);
    for (int l = 0; l < 2; ++l) {
        tcat_kernel<<<tgrid(1536 * 1024), blk, 0, stream>>>(
            W_ioux + (size_t)l * 512 * 1536, W_iouh + (size_t)l * 512 * 1536,
            wt_iou_cat + (size_t)l * 1536 * 1024, 1536, 1536 * 1024);
        tcat_kernel<<<tgrid(512 * 1024), blk, 0, stream>>>(
            W_fx + (size_t)l * 512 * 512, W_fh + (size_t)l * 512 * 512,
            wt_f_cat + (size_t)l * 512 * 1024, 512, 512 * 1024);
    }

    auto gemm = [&](const bf16* A1, int a1shift, const bf16* A2,
                    const bf16* Bt, int bstride, int ksegs,
                    float* Cf, bf16* Cb, const float* b1, const float* b2,
                    int M, int N, int relu) {
        dim3 grid((unsigned)((M + 127) / 128), (unsigned)(N / 128));
        gemm_frag_kernel<<<grid, blk, 0, stream>>>(A1, a1shift, A2, Bt, bstride,
                                                   ksegs, Cf, Cb, b1, b2, M, N, relu);
    };

    // --- input projection: h = relu(x @ W_in + b_in) ---
    convx_kernel<<<tgrid(NN * 128), blk, 0, stream>>>(x, xbf, NN * 128);
    gemm(xbf, 0, nullptr, wt_in, 512, 1, nullptr, h, b_in, nullptr, NN, 512, 1);

    for (int l = 0; l < 2; ++l) {
        const bf16* wiou = wt_iou_cat + (size_t)l * 1536 * 1024;
        const bf16* wf   = wt_f_cat + (size_t)l * 512 * 1024;
        const float* bx1 = b_ioux + (size_t)l * 1536;
        const float* bx2 = b_iouh + (size_t)l * 1536;
        const float* bf1 = b_fx + (size_t)l * 512;
        const float* bf2 = b_fh + (size_t)l * 512;

        // leaves + level-7 parents, pipelined in 8 chunks
        for (int c = 0; c < 8; ++c) {
            int lr0 = LEAF_START + 8192 * c;   // leaf rows [lr0, lr0+8192)
            gemm(h + (size_t)lr0 * 512, 0, nullptr, wiou, 1024, 1,
                 nullptr, IOU, bx1, bx2, 8192, 1536, 0);
            leaf_ew_kernel<<<tgrid(8192 * 64), blk, 0, stream>>>(
                IOU, h + (size_t)lr0 * 512, cell_leaf, 8192 * 64);
            int p0  = 5461 + 2048 * c;         // level-7 parents
            int cs0 = 4 * p0 + 1;              // == lr0
            hs_kernel<<<tgrid(2048 * 64), blk, 0, stream>>>(
                h + (size_t)cs0 * 512, HS, 2048 * 64);
            gemm(h + (size_t)p0 * 512, 0, HS, wiou, 1024, 2,
                 nullptr, IOU, bx1, bx2, 2048, 1536, 0);
            gemm(h + (size_t)p0 * 512, 2, h + (size_t)cs0 * 512, wf, 1024, 2,
                 nullptr, CF, bf1, bf2, 4 * 2048, 512, 0);
            internal_ew_kernel<<<tgrid(2048 * 64), blk, 0, stream>>>(
                IOU, CF, cell_leaf, h + (size_t)p0 * 512,
                cell_int + (size_t)p0 * 512, 2048 * 64);
        }
        // levels 6..0
        for (int d = 6; d >= 0; --d) {
            int s  = LS[d];
            int E  = LS[d + 1] - LS[d];
            int cs = 4 * s + 1;                // == LS[d+1]
            hs_kernel<<<tgrid(E * 64), blk, 0, stream>>>(
                h + (size_t)cs * 512, HS, E * 64);
            gemm(h + (size_t)s * 512, 0, HS, wiou, 1024, 2,
                 nullptr, IOU, bx1, bx2, E, 1536, 0);
            gemm(h + (size_t)s * 512, 2, h + (size_t)cs * 512, wf, 1024, 2,
                 nullptr, CF, bf1, bf2, 4 * E, 512, 0);
            internal_ew_kernel<<<tgrid(E * 64), blk, 0, stream>>>(
                IOU, CF, cell_int + (size_t)cs * 512, h + (size_t)s * 512,
                cell_int + (size_t)s * 512, E * 64);
        }
    }

    // --- output projection + tree reduction ---
    float* node_emb = (float*)d_out;
    gemm(h, 0, nullptr, wt_out, 512, 1, node_emb, nullptr, b_out, nullptr, NN, 256, 0);
    reduce_partial_kernel<<<dim3(256), blk, 0, stream>>>(node_emb, partial, NN);
    reduce_final_kernel<<<dim3(1), blk, 0, stream>>>(partial, node_emb + (size_t)NN * 256);
}

// Round 4
// 2923.061 us; speedup vs baseline: 1.3776x; 1.0724x over previous
//
#include <hip/hip_runtime.h>

typedef __bf16 bf16;
typedef __bf16 bf16x8 __attribute__((ext_vector_type(8)));
typedef float f32x4 __attribute__((ext_vector_type(4)));

#define NN 87381
#define NINT 21845
#define NLEAF 65536
#define LEAF_START 21845

__device__ __forceinline__ float sigmoidf_(float x) {
    return 1.0f / (1.0f + __expf(-x));
}
__device__ __forceinline__ float tanhf_(float x) {
    return 1.0f - 2.0f / (__expf(2.0f * x) + 1.0f);
}

// async 16B global -> LDS (lane-contiguous dest required)
__device__ __forceinline__ void gload_lds16(const bf16* g, bf16* l) {
    __builtin_amdgcn_global_load_lds(
        (const __attribute__((address_space(1))) unsigned int*)g,
        (__attribute__((address_space(3))) unsigned int*)l, 16, 0, 0);
}

// ---------------------------------------------------------------------------
// W (512 x NR fp32, row-major) -> Wt (NR x 512 bf16)
__global__ void tconv_kernel(const float* __restrict__ W, bf16* __restrict__ Wt,
                             int NR, int total) {
    int idx = blockIdx.x * 256 + threadIdx.x;
    if (idx >= total) return;
    int n = idx >> 9;
    int k = idx & 511;
    Wt[idx] = (bf16)W[(size_t)k * NR + n];
}

// W1,W2 (each 512 x NR fp32) -> Wt (NR x 1024 bf16), row n = [W1[:,n] | W2[:,n]]
__global__ void tcat_kernel(const float* __restrict__ W1, const float* __restrict__ W2,
                            bf16* __restrict__ Wt, int NR, int total) {
    int idx = blockIdx.x * 256 + threadIdx.x;
    if (idx >= total) return;
    int n = idx >> 10;
    int kk = idx & 1023;
    const float* src = (kk < 512) ? W1 : W2;
    int k = kk & 511;
    Wt[idx] = (bf16)src[(size_t)k * NR + n];
}

// x fp32 -> bf16, vectorized (4 floats / thread)
__global__ void convx_kernel(const float* __restrict__ X, bf16* __restrict__ Y, int total4) {
    int idx = blockIdx.x * 256 + threadIdx.x;
    if (idx >= total4) return;
    const float4 f = *reinterpret_cast<const float4*>(X + (size_t)idx * 4);
    bf16 o[4] = {(bf16)f.x, (bf16)f.y, (bf16)f.z, (bf16)f.w};
    *reinterpret_cast<ushort2*>(Y + (size_t)idx * 4 + 0) = *reinterpret_cast<ushort2*>(&o[0]);
    *reinterpret_cast<ushort2*>(Y + (size_t)idx * 4 + 2) = *reinterpret_cast<ushort2*>(&o[2]);
}

// ---------------------------------------------------------------------------
// Shared MFMA compute core: A-tile/B-tile in LDS (128x64 unpadded), 4 waves.
#define MFMA_COMPUTE(As, Bs, acc, wm, wn, lm, quad)                              \
    _Pragma("unroll")                                                            \
    for (int kk = 0; kk < 64; kk += 32) {                                        \
        bf16x8 areg[4], breg[4];                                                 \
        _Pragma("unroll")                                                        \
        for (int mi = 0; mi < 4; ++mi)                                           \
            areg[mi] = *reinterpret_cast<const bf16x8*>(                         \
                &As[(wm + mi * 16 + lm) * 64 + kk + quad * 8]);                  \
        _Pragma("unroll")                                                        \
        for (int ni = 0; ni < 4; ++ni)                                           \
            breg[ni] = *reinterpret_cast<const bf16x8*>(                         \
                &Bs[(wn + ni * 16 + lm) * 64 + kk + quad * 8]);                  \
        _Pragma("unroll")                                                        \
        for (int mi = 0; mi < 4; ++mi)                                           \
            _Pragma("unroll")                                                    \
            for (int ni = 0; ni < 4; ++ni)                                       \
                acc[mi][ni] = __builtin_amdgcn_mfma_f32_16x16x32_bf16(           \
                    areg[mi], breg[ni], acc[mi][ni], 0, 0, 0);                   \
    }

// Plain GEMM: C[M x N] = A[M x K] @ Bt[N x K]^T + b1 + b2 (Bt ld = bstride).
__global__ __launch_bounds__(256)
void gemm_kernel(const bf16* __restrict__ A, const bf16* __restrict__ Bt,
                 int bstride, int K,
                 float* __restrict__ Cf, bf16* __restrict__ Cb,
                 const float* __restrict__ bias1, const float* __restrict__ bias2,
                 int M, int N, int relu)
{
    __shared__ __align__(16) bf16 As[128 * 64];
    __shared__ __align__(16) bf16 Bs[128 * 64];
    const int tid  = threadIdx.x;
    const int wave = tid >> 6;
    const int lane = tid & 63;
    const int bm = blockIdx.x * 128;
    const int bn = blockIdx.y * 128;
    const int wm = (wave & 1) * 64;
    const int wn = (wave >> 1) * 64;
    const int lm   = lane & 15;
    const int quad = lane >> 4;

    f32x4 acc[4][4];
#pragma unroll
    for (int i = 0; i < 4; ++i)
#pragma unroll
        for (int j = 0; j < 4; ++j) acc[i][j] = (f32x4){0.f, 0.f, 0.f, 0.f};

    for (int k0 = 0; k0 < K; k0 += 64) {
#pragma unroll
        for (int i = 0; i < 4; ++i) {
            int c  = i * 256 + tid;
            int r  = c >> 3;
            int kc = (c & 7) << 3;
            int gr = bm + r; gr = (gr < M) ? gr : (M - 1);
            gload_lds16(A + (size_t)gr * K + k0 + kc, &As[c << 3]);
        }
#pragma unroll
        for (int i = 0; i < 4; ++i) {
            int c  = i * 256 + tid;
            int r  = c >> 3;
            int kc = (c & 7) << 3;
            gload_lds16(Bt + (size_t)(bn + r) * bstride + k0 + kc, &Bs[c << 3]);
        }
        __syncthreads();
        MFMA_COMPUTE(As, Bs, acc, wm, wn, lm, quad);
        __syncthreads();
    }

#pragma unroll
    for (int ni = 0; ni < 4; ++ni) {
        int col = bn + wn + ni * 16 + lm;
        float bsum = (bias1 ? bias1[col] : 0.f) + (bias2 ? bias2[col] : 0.f);
#pragma unroll
        for (int mi = 0; mi < 4; ++mi) {
#pragma unroll
            for (int r = 0; r < 4; ++r) {
                int row = bm + wm + mi * 16 + quad * 4 + r;
                if (row < M) {
                    float v = acc[mi][ni][r] + bsum;
                    if (relu) v = (v > 0.f) ? v : 0.f;
                    if (Cf) Cf[(size_t)row * N + col] = v;
                    else    Cb[(size_t)row * N + col] = (bf16)v;
                }
            }
        }
    }
}

// ---------------------------------------------------------------------------
// Fused per-level kernel: one dispatch computes BOTH
//   IOU[E x 1536]  = [h_parent | sum4(h_child)] @ wiou^T + bx1 + bx2   (y in 0..11)
//   CF [4E x 512]  = [h_parent(bcast4) | h_child] @ wf^T + bf1 + bf2    (y in 12..15)
// Children of local parent m are h rows cs+4m..cs+4m+3; parents at s+m.
// HS (child hidden sum) is computed on the fly during seg-1 A staging.
__global__ __launch_bounds__(256)
void level_kernel(const bf16* __restrict__ h, int s, int cs, int E,
                  const bf16* __restrict__ wiou, const bf16* __restrict__ wf,
                  const float* __restrict__ bx1, const float* __restrict__ bx2,
                  const float* __restrict__ bf1, const float* __restrict__ bf2,
                  bf16* __restrict__ IOU, bf16* __restrict__ CF)
{
    const bool isCF = (blockIdx.y >= 12);
    const int M = isCF ? 4 * E : E;
    const int bm = blockIdx.x * 128;
    if (bm >= M) return;
    const int bn = (isCF ? (blockIdx.y - 12) : blockIdx.y) * 128;

    __shared__ __align__(16) bf16 As[128 * 64];
    __shared__ __align__(16) bf16 Bs[128 * 64];
    const int tid  = threadIdx.x;
    const int wave = tid >> 6;
    const int lane = tid & 63;
    const int wm = (wave & 1) * 64;
    const int wn = (wave >> 1) * 64;
    const int lm   = lane & 15;
    const int quad = lane >> 4;

    f32x4 acc[4][4];
#pragma unroll
    for (int i = 0; i < 4; ++i)
#pragma unroll
        for (int j = 0; j < 4; ++j) acc[i][j] = (f32x4){0.f, 0.f, 0.f, 0.f};

    const bf16* __restrict__ Bt = isCF ? wf : wiou;

    for (int k0 = 0; k0 < 1024; k0 += 64) {
        const int seg   = k0 >> 9;
        const int kseg0 = k0 & 511;
        if (!isCF && seg == 1) {
            // A = HS rows: sum of 4 child rows, computed in-register -> ds_write
#pragma unroll
            for (int i = 0; i < 4; ++i) {
                int c  = i * 256 + tid;
                int r  = c >> 3;
                int kc = (c & 7) << 3;
                int gr = bm + r; gr = (gr < E) ? gr : (E - 1);
                const bf16* cb = h + ((size_t)(cs + 4 * gr) << 9) + kseg0 + kc;
                float a8[8];
#pragma unroll
                for (int t = 0; t < 8; ++t) a8[t] = 0.f;
#pragma unroll
                for (int k = 0; k < 4; ++k) {
                    const bf16x8 v = *reinterpret_cast<const bf16x8*>(cb + (k << 9));
#pragma unroll
                    for (int t = 0; t < 8; ++t) a8[t] += (float)v[t];
                }
                bf16x8 o;
#pragma unroll
                for (int t = 0; t < 8; ++t) o[t] = (bf16)a8[t];
                *reinterpret_cast<bf16x8*>(&As[c << 3]) = o;
            }
        } else {
#pragma unroll
            for (int i = 0; i < 4; ++i) {
                int c  = i * 256 + tid;
                int r  = c >> 3;
                int kc = (c & 7) << 3;
                int gr = bm + r; gr = (gr < M) ? gr : (M - 1);
                int arow;
                if (!isCF)          arow = s + gr;            // parent rows, seg0
                else if (seg == 0)  arow = s + (gr >> 2);     // parent bcast4
                else                arow = cs + gr;           // child rows
                gload_lds16(h + ((size_t)arow << 9) + kseg0 + kc, &As[c << 3]);
            }
        }
#pragma unroll
        for (int i = 0; i < 4; ++i) {
            int c  = i * 256 + tid;
            int r  = c >> 3;
            int kc = (c & 7) << 3;
            gload_lds16(Bt + (size_t)(bn + r) * 1024 + k0 + kc, &Bs[c << 3]);
        }
        __syncthreads();
        MFMA_COMPUTE(As, Bs, acc, wm, wn, lm, quad);
        __syncthreads();
    }

    const int N = isCF ? 512 : 1536;
    bf16* __restrict__ out = isCF ? CF : IOU;
    const float* b1 = isCF ? bf1 : bx1;
    const float* b2 = isCF ? bf2 : bx2;
#pragma unroll
    for (int ni = 0; ni < 4; ++ni) {
        int col = bn + wn + ni * 16 + lm;
        float bsum = b1[col] + b2[col];
#pragma unroll
        for (int mi = 0; mi < 4; ++mi) {
#pragma unroll
            for (int r = 0; r < 4; ++r) {
                int row = bm + wm + mi * 16 + quad * 4 + r;
                if (row < M)
                    out[(size_t)row * N + col] = (bf16)(acc[mi][ni][r] + bsum);
            }
        }
    }
}

// ---------------------------------------------------------------------------
// Leaf elementwise (x8 vectorized): IOU full preact -> h, cell.
__global__ void leaf_ew_kernel(const bf16* __restrict__ IOU, bf16* __restrict__ h_out,
                               float* __restrict__ cell_out, int total8)
{
    int idx = blockIdx.x * 256 + threadIdx.x;
    if (idx >= total8) return;
    int m  = idx >> 6;
    int j0 = (idx & 63) << 3;
    size_t r3 = (size_t)m * 1536 + j0;
    const bf16x8 iv = *reinterpret_cast<const bf16x8*>(&IOU[r3]);
    const bf16x8 ov = *reinterpret_cast<const bf16x8*>(&IOU[r3 + 512]);
    const bf16x8 uv = *reinterpret_cast<const bf16x8*>(&IOU[r3 + 1024]);
    bf16x8 hv;
    float cv[8];
#pragma unroll
    for (int t = 0; t < 8; ++t) {
        float i_ = sigmoidf_((float)iv[t]);
        float o_ = sigmoidf_((float)ov[t]);
        float u_ = tanhf_((float)uv[t]);
        float c = i_ * u_;
        cv[t] = c;
        hv[t] = (bf16)(o_ * tanhf_(c));
    }
    *reinterpret_cast<bf16x8*>(&h_out[(size_t)idx * 8]) = hv;
    *reinterpret_cast<float4*>(&cell_out[(size_t)idx * 8])     = *reinterpret_cast<float4*>(&cv[0]);
    *reinterpret_cast<float4*>(&cell_out[(size_t)idx * 8 + 4]) = *reinterpret_cast<float4*>(&cv[4]);
}

// Internal-node elementwise (x8): IOU (E x 1536), CF (4E x 512), cellc (4E x 512 fp32).
__global__ void internal_ew_kernel(const bf16* __restrict__ IOU, const bf16* __restrict__ CF,
                                   const float* __restrict__ cellc, bf16* __restrict__ h_out,
                                   float* __restrict__ cell_out, int total8)
{
    int idx = blockIdx.x * 256 + threadIdx.x;
    if (idx >= total8) return;
    int m  = idx >> 6;
    int j0 = (idx & 63) << 3;
    size_t r3 = (size_t)m * 1536 + j0;
    const bf16x8 iv = *reinterpret_cast<const bf16x8*>(&IOU[r3]);
    const bf16x8 ov = *reinterpret_cast<const bf16x8*>(&IOU[r3 + 512]);
    const bf16x8 uv = *reinterpret_cast<const bf16x8*>(&IOU[r3 + 1024]);
    float accv[8];
#pragma unroll
    for (int t = 0; t < 8; ++t) accv[t] = 0.f;
#pragma unroll
    for (int k = 0; k < 4; ++k) {
        size_t cr = (size_t)(4 * m + k) * 512 + j0;
        const bf16x8 fv = *reinterpret_cast<const bf16x8*>(&CF[cr]);
        const float4 c0 = *reinterpret_cast<const float4*>(&cellc[cr]);
        const float4 c1 = *reinterpret_cast<const float4*>(&cellc[cr + 4]);
        const float cc[8] = {c0.x, c0.y, c0.z, c0.w, c1.x, c1.y, c1.z, c1.w};
#pragma unroll
        for (int t = 0; t < 8; ++t) accv[t] += sigmoidf_((float)fv[t]) * cc[t];
    }
    bf16x8 hv;
    float cv[8];
#pragma unroll
    for (int t = 0; t < 8; ++t) {
        float i_ = sigmoidf_((float)iv[t]);
        float o_ = sigmoidf_((float)ov[t]);
        float u_ = tanhf_((float)uv[t]);
        float c = i_ * u_ + accv[t];
        cv[t] = c;
        hv[t] = (bf16)(o_ * tanhf_(c));
    }
    *reinterpret_cast<bf16x8*>(&h_out[(size_t)idx * 8]) = hv;
    *reinterpret_cast<float4*>(&cell_out[(size_t)idx * 8])     = *reinterpret_cast<float4*>(&cv[0]);
    *reinterpret_cast<float4*>(&cell_out[(size_t)idx * 8 + 4]) = *reinterpret_cast<float4*>(&cv[4]);
}

// ---------------------------------------------------------------------------
// tree_emb = column sum of node_emb, 3-stage parallel reduction
#define R1_BLOCKS 2048
#define R1_ROWS 43          // 2048*43 = 88064 >= 87381
__global__ void reduce1_kernel(const float* __restrict__ ne, float* __restrict__ partial)
{
    int t = threadIdx.x;
    int b = blockIdx.x;
    int r0 = b * R1_ROWS;
    int r1 = r0 + R1_ROWS; r1 = (r1 < NN) ? r1 : NN;
    float acc = 0.f;
    for (int r = r0; r < r1; ++r) acc += ne[(size_t)r * 256 + t];
    partial[(size_t)b * 256 + t] = acc;
}
__global__ void reduce2_kernel(const float* __restrict__ partial, float* __restrict__ partial2)
{
    int t = threadIdx.x;
    int b = blockIdx.x;      // 0..63
    float acc = 0.f;
    for (int i = 0; i < 32; ++i) acc += partial[(size_t)(b * 32 + i) * 256 + t];
    partial2[(size_t)b * 256 + t] = acc;
}
__global__ void reduce3_kernel(const float* __restrict__ partial2, float* __restrict__ tree)
{
    int t = threadIdx.x;
    float acc = 0.f;
    for (int i = 0; i < 64; ++i) acc += partial2[(size_t)i * 256 + t];
    tree[t] = acc;
}

// ---------------------------------------------------------------------------
extern "C" void kernel_launch(void* const* d_in, const int* in_sizes, int n_in,
                              void* d_out, int out_size, void* d_ws, size_t ws_size,
                              hipStream_t stream)
{
    const float* x      = (const float*)d_in[0];
    const float* W_in   = (const float*)d_in[8];
    const float* b_in   = (const float*)d_in[9];
    const float* W_ioux = (const float*)d_in[10];
    const float* b_ioux = (const float*)d_in[11];
    const float* W_iouh = (const float*)d_in[12];
    const float* b_iouh = (const float*)d_in[13];
    const float* W_fx   = (const float*)d_in[14];
    const float* b_fx   = (const float*)d_in[15];
    const float* W_fh   = (const float*)d_in[16];
    const float* b_fh   = (const float*)d_in[17];
    const float* W_out  = (const float*)d_in[18];
    const float* b_out  = (const float*)d_in[19];

    static const int LS[10] = {0, 1, 5, 21, 85, 341, 1365, 5461, 21845, 87381};

    char* ws = (char*)d_ws;
    size_t off = 0;
    auto take = [&](size_t bytes) -> void* {
        void* p = ws + off;
        off += (bytes + 255) & ~(size_t)255;
        return p;
    };
    bf16*  wt_in      = (bf16*) take((size_t)512 * 512 * 2);
    bf16*  wt_out     = (bf16*) take((size_t)256 * 512 * 2);
    bf16*  wt_iou_cat = (bf16*) take((size_t)2 * 1536 * 1024 * 2);
    bf16*  wt_f_cat   = (bf16*) take((size_t)2 * 512 * 1024 * 2);
    bf16*  h          = (bf16*) take((size_t)NN * 512 * 2);
    float* cell_int   = (float*)take((size_t)NINT * 512 * 4);
    float* cell_leaf  = (float*)take((size_t)8192 * 512 * 4);
    bf16*  IOU        = (bf16*) take((size_t)8192 * 1536 * 2);
    bf16*  CF         = (bf16*) take((size_t)16384 * 512 * 2);
    float* partial    = (float*)take((size_t)R1_BLOCKS * 256 * 4);
    float* partial2   = (float*)take((size_t)64 * 256 * 4);
    // x-as-bf16 staging aliases cell/IOU region (all dead during input proj)
    bf16*  xbf        = (bf16*)cell_int;

    dim3 blk(256);
    auto tgrid = [](int total) { return dim3((unsigned)((total + 255) / 256)); };

    // --- weight transpose+convert (~9 MB, one pass) ---
    tconv_kernel<<<tgrid(512 * 512), blk, 0, stream>>>(W_in, wt_in, 512, 512 * 512);
    tconv_kernel<<<tgrid(256 * 512), blk, 0, stream>>>(W_out, wt_out, 256, 256 * 512);
    for (int l = 0; l < 2; ++l) {
        tcat_kernel<<<tgrid(1536 * 1024), blk, 0, stream>>>(
            W_ioux + (size_t)l * 512 * 1536, W_iouh + (size_t)l * 512 * 1536,
            wt_iou_cat + (size_t)l * 1536 * 1024, 1536, 1536 * 1024);
        tcat_kernel<<<tgrid(512 * 1024), blk, 0, stream>>>(
            W_fx + (size_t)l * 512 * 512, W_fh + (size_t)l * 512 * 512,
            wt_f_cat + (size_t)l * 512 * 1024, 512, 512 * 1024);
    }

    auto gemm = [&](const bf16* A, const bf16* Bt, int bstride, int K,
                    float* Cf, bf16* Cb, const float* b1, const float* b2,
                    int M, int N, int relu) {
        dim3 grid((unsigned)((M + 127) / 128), (unsigned)(N / 128));
        gemm_kernel<<<grid, blk, 0, stream>>>(A, Bt, bstride, K, Cf, Cb, b1, b2, M, N, relu);
    };

    // --- input projection: h = relu(x @ W_in + b_in) ---
    convx_kernel<<<tgrid(NN * 128), blk, 0, stream>>>(x, xbf, NN * 128);
    gemm(xbf, wt_in, 512, 512, nullptr, h, b_in, nullptr, NN, 512, 1);

    for (int l = 0; l < 2; ++l) {
        const bf16* wiou = wt_iou_cat + (size_t)l * 1536 * 1024;
        const bf16* wf   = wt_f_cat + (size_t)l * 512 * 1024;
        const float* bx1 = b_ioux + (size_t)l * 1536;
        const float* bx2 = b_iouh + (size_t)l * 1536;
        const float* bf1 = b_fx + (size_t)l * 512;
        const float* bf2 = b_fh + (size_t)l * 512;

        // leaves + level-7 parents, pipelined in 8 chunks
        for (int c = 0; c < 8; ++c) {
            int lr0 = LEAF_START + 8192 * c;   // leaf rows [lr0, lr0+8192)
            gemm(h + (size_t)lr0 * 512, wiou, 1024, 512,
                 nullptr, IOU, bx1, bx2, 8192, 1536, 0);
            leaf_ew_kernel<<<tgrid(8192 * 64), blk, 0, stream>>>(
                IOU, h + (size_t)lr0 * 512, cell_leaf, 8192 * 64);
            int p0  = 5461 + 2048 * c;         // level-7 parents
            int cs0 = 4 * p0 + 1;              // == lr0
            {
                dim3 grid((unsigned)((4 * 2048 + 127) / 128), 16);
                level_kernel<<<grid, blk, 0, stream>>>(h, p0, cs0, 2048, wiou, wf,
                                                       bx1, bx2, bf1, bf2, IOU, CF);
            }
            internal_ew_kernel<<<tgrid(2048 * 64), blk, 0, stream>>>(
                IOU, CF, cell_leaf, h + (size_t)p0 * 512,
                cell_int + (size_t)p0 * 512, 2048 * 64);
        }
        // levels 6..0
        for (int d = 6; d >= 0; --d) {
            int s  = LS[d];
            int E  = LS[d + 1] - LS[d];
            int cs = 4 * s + 1;                // == LS[d+1]
            {
                dim3 grid((unsigned)((4 * E + 127) / 128), 16);
                level_kernel<<<grid, blk, 0, stream>>>(h, s, cs, E, wiou, wf,
                                                       bx1, bx2, bf1, bf2, IOU, CF);
            }
            internal_ew_kernel<<<tgrid(E * 64), blk, 0, stream>>>(
                IOU, CF, cell_int + (size_t)cs * 512, h + (size_t)s * 512,
                cell_int + (size_t)s * 512, E * 64);
        }
    }

    // --- output projection + tree reduction ---
    float* node_emb = (float*)d_out;
    gemm(h, wt_out, 512, 512, node_emb, nullptr, b_out, nullptr, NN, 256, 0);
    reduce1_kernel<<<dim3(R1_BLOCKS), blk, 0, stream>>>(node_emb, partial);
    reduce2_kernel<<<dim3(64), blk, 0, stream>>>(partial, partial2);
    reduce3_kernel<<<dim3(1), blk, 0, stream>>>(partial2, node_emb + (size_t)NN * 256);
}

// Round 5
// 2365.539 us; speedup vs baseline: 1.7022x; 1.2357x over previous
//
#include <hip/hip_runtime.h>

typedef __bf16 bf16;
typedef __bf16 bf16x8 __attribute__((ext_vector_type(8)));
typedef float f32x4 __attribute__((ext_vector_type(4)));

#define NN 87381
#define NINT 21845
#define NLEAF 65536
#define LEAF_START 21845

__device__ __forceinline__ float sigmoidf_(float x) {
    return 1.0f / (1.0f + __expf(-x));
}
__device__ __forceinline__ float tanhf_(float x) {
    return 1.0f - 2.0f / (__expf(2.0f * x) + 1.0f);
}

// async 16B global -> LDS (lane-contiguous dest required)
__device__ __forceinline__ void gload_lds16(const bf16* g, bf16* l) {
    __builtin_amdgcn_global_load_lds(
        (const __attribute__((address_space(1))) unsigned int*)g,
        (__attribute__((address_space(3))) unsigned int*)l, 16, 0, 0);
}

// XOR-swizzled LDS chunk index for (row, kchunk): kills the 16-way bank
// conflict of the unpadded 128x64 layout (row stride 128 B == 32 banks).
// chunk -> byte offset is chunk*16; element offset chunk*8.
#define SWZ(r, kc) ((((r) << 3) | ((kc) ^ ((r) & 7))) << 3)

// ---------------------------------------------------------------------------
// W (512 x NR fp32, row-major) -> Wt (NR x 512 bf16)
__global__ void tconv_kernel(const float* __restrict__ W, bf16* __restrict__ Wt,
                             int NR, int total) {
    int idx = blockIdx.x * 256 + threadIdx.x;
    if (idx >= total) return;
    int n = idx >> 9;
    int k = idx & 511;
    Wt[idx] = (bf16)W[(size_t)k * NR + n];
}

// W1,W2 (each 512 x NR fp32) -> Wt (NR x 1024 bf16), row n = [W1[:,n] | W2[:,n]]
__global__ void tcat_kernel(const float* __restrict__ W1, const float* __restrict__ W2,
                            bf16* __restrict__ Wt, int NR, int total) {
    int idx = blockIdx.x * 256 + threadIdx.x;
    if (idx >= total) return;
    int n = idx >> 10;
    int kk = idx & 1023;
    const float* src = (kk < 512) ? W1 : W2;
    int k = kk & 511;
    Wt[idx] = (bf16)src[(size_t)k * NR + n];
}

// x fp32 -> bf16, vectorized (4 floats / thread)
__global__ void convx_kernel(const float* __restrict__ X, bf16* __restrict__ Y, int total4) {
    int idx = blockIdx.x * 256 + threadIdx.x;
    if (idx >= total4) return;
    const float4 f = *reinterpret_cast<const float4*>(X + (size_t)idx * 4);
    bf16 o[4] = {(bf16)f.x, (bf16)f.y, (bf16)f.z, (bf16)f.w};
    *reinterpret_cast<ushort2*>(Y + (size_t)idx * 4 + 0) = *reinterpret_cast<ushort2*>(&o[0]);
    *reinterpret_cast<ushort2*>(Y + (size_t)idx * 4 + 2) = *reinterpret_cast<ushort2*>(&o[2]);
}

// ---------------------------------------------------------------------------
// Shared MFMA compute core over swizzled LDS tiles.
#define MFMA_COMPUTE(As, Bs, acc, wm, wn, lm, quad)                              \
    _Pragma("unroll")                                                            \
    for (int kk = 0; kk < 64; kk += 32) {                                        \
        const int kc_ = (kk >> 3) + quad;                                        \
        bf16x8 areg[4], breg[4];                                                 \
        _Pragma("unroll")                                                        \
        for (int mi = 0; mi < 4; ++mi)                                           \
            areg[mi] = *reinterpret_cast<const bf16x8*>(                         \
                &As[SWZ(wm + mi * 16 + lm, kc_)]);                               \
        _Pragma("unroll")                                                        \
        for (int ni = 0; ni < 4; ++ni)                                           \
            breg[ni] = *reinterpret_cast<const bf16x8*>(                         \
                &Bs[SWZ(wn + ni * 16 + lm, kc_)]);                               \
        _Pragma("unroll")                                                        \
        for (int mi = 0; mi < 4; ++mi)                                           \
            _Pragma("unroll")                                                    \
            for (int ni = 0; ni < 4; ++ni)                                       \
                acc[mi][ni] = __builtin_amdgcn_mfma_f32_16x16x32_bf16(           \
                    areg[mi], breg[ni], acc[mi][ni], 0, 0, 0);                   \
    }

// Plain GEMM: C[M x N] = A[M x K] @ Bt[N x K]^T + b1 + b2 (Bt ld = bstride).
// 1D grid, col-fastest block order (A row-tile shared by nt consecutive blocks).
__global__ __launch_bounds__(256)
void gemm_kernel(const bf16* __restrict__ A, const bf16* __restrict__ Bt,
                 int bstride, int K, int ntiles,
                 float* __restrict__ Cf, bf16* __restrict__ Cb,
                 const float* __restrict__ bias1, const float* __restrict__ bias2,
                 int M, int N, int relu)
{
    __shared__ __align__(16) bf16 As[128 * 64];
    __shared__ __align__(16) bf16 Bs[128 * 64];
    const int tid  = threadIdx.x;
    const int wave = tid >> 6;
    const int lane = tid & 63;
    const int bm = (blockIdx.x / ntiles) * 128;
    const int bn = (blockIdx.x % ntiles) * 128;
    const int wm = (wave & 1) * 64;
    const int wn = (wave >> 1) * 64;
    const int lm   = lane & 15;
    const int quad = lane >> 4;

    f32x4 acc[4][4];
#pragma unroll
    for (int i = 0; i < 4; ++i)
#pragma unroll
        for (int j = 0; j < 4; ++j) acc[i][j] = (f32x4){0.f, 0.f, 0.f, 0.f};

    for (int k0 = 0; k0 < K; k0 += 64) {
#pragma unroll
        for (int i = 0; i < 4; ++i) {
            int c   = i * 256 + tid;
            int r   = c >> 3;
            int kc8 = ((c & 7) ^ (r & 7)) << 3;   // swizzled source k-offset
            int gr  = bm + r; gr = (gr < M) ? gr : (M - 1);
            gload_lds16(A + (size_t)gr * K + k0 + kc8, &As[c << 3]);
        }
#pragma unroll
        for (int i = 0; i < 4; ++i) {
            int c   = i * 256 + tid;
            int r   = c >> 3;
            int kc8 = ((c & 7) ^ (r & 7)) << 3;
            gload_lds16(Bt + (size_t)(bn + r) * bstride + k0 + kc8, &Bs[c << 3]);
        }
        __syncthreads();
        MFMA_COMPUTE(As, Bs, acc, wm, wn, lm, quad);
        __syncthreads();
    }

#pragma unroll
    for (int ni = 0; ni < 4; ++ni) {
        int col = bn + wn + ni * 16 + lm;
        float bsum = (bias1 ? bias1[col] : 0.f) + (bias2 ? bias2[col] : 0.f);
#pragma unroll
        for (int mi = 0; mi < 4; ++mi) {
#pragma unroll
            for (int r = 0; r < 4; ++r) {
                int row = bm + wm + mi * 16 + quad * 4 + r;
                if (row < M) {
                    float v = acc[mi][ni][r] + bsum;
                    if (relu) v = (v > 0.f) ? v : 0.f;
                    if (Cf) Cf[(size_t)row * N + col] = v;
                    else    Cb[(size_t)row * N + col] = (bf16)v;
                }
            }
        }
    }
}

// ---------------------------------------------------------------------------
// Fused per-level kernel (1D grid, col-fastest in each role):
//   blocks [0, iou_mt*12):   IOU[E x 1536] = [h_par | sum4(h_child)] @ wiou^T + bx1+bx2
//   blocks [iou_mt*12, ..):  CF [4E x 512] = [h_par(bcast4) | h_child] @ wf^T + bf1+bf2
__global__ __launch_bounds__(256)
void level_kernel(const bf16* __restrict__ h, int s, int cs, int E, int iou_blocks,
                  const bf16* __restrict__ wiou, const bf16* __restrict__ wf,
                  const float* __restrict__ bx1, const float* __restrict__ bx2,
                  const float* __restrict__ bf1, const float* __restrict__ bf2,
                  bf16* __restrict__ IOU, bf16* __restrict__ CF)
{
    const bool isCF = ((int)blockIdx.x >= iou_blocks);
    const int bx = isCF ? (blockIdx.x - iou_blocks) : blockIdx.x;
    const int nt = isCF ? 4 : 12;
    const int M  = isCF ? 4 * E : E;
    const int bm = (bx / nt) * 128;
    if (bm >= M) return;
    const int bn = (bx % nt) * 128;

    __shared__ __align__(16) bf16 As[128 * 64];
    __shared__ __align__(16) bf16 Bs[128 * 64];
    const int tid  = threadIdx.x;
    const int wave = tid >> 6;
    const int lane = tid & 63;
    const int wm = (wave & 1) * 64;
    const int wn = (wave >> 1) * 64;
    const int lm   = lane & 15;
    const int quad = lane >> 4;

    f32x4 acc[4][4];
#pragma unroll
    for (int i = 0; i < 4; ++i)
#pragma unroll
        for (int j = 0; j < 4; ++j) acc[i][j] = (f32x4){0.f, 0.f, 0.f, 0.f};

    const bf16* __restrict__ Bt = isCF ? wf : wiou;

    for (int k0 = 0; k0 < 1024; k0 += 64) {
        const int seg   = k0 >> 9;
        const int kseg0 = k0 & 511;
        if (!isCF && seg == 1) {
            // A = HS rows: sum of 4 child rows, in-register -> ds_write (swizzled)
#pragma unroll
            for (int i = 0; i < 4; ++i) {
                int c   = i * 256 + tid;
                int r   = c >> 3;
                int kc8 = ((c & 7) ^ (r & 7)) << 3;
                int gr  = bm + r; gr = (gr < E) ? gr : (E - 1);
                const bf16* cb = h + ((size_t)(cs + 4 * gr) << 9) + kseg0 + kc8;
                float a8[8];
#pragma unroll
                for (int t = 0; t < 8; ++t) a8[t] = 0.f;
#pragma unroll
                for (int k = 0; k < 4; ++k) {
                    const bf16x8 v = *reinterpret_cast<const bf16x8*>(cb + (k << 9));
#pragma unroll
                    for (int t = 0; t < 8; ++t) a8[t] += (float)v[t];
                }
                bf16x8 o;
#pragma unroll
                for (int t = 0; t < 8; ++t) o[t] = (bf16)a8[t];
                *reinterpret_cast<bf16x8*>(&As[c << 3]) = o;
            }
        } else {
#pragma unroll
            for (int i = 0; i < 4; ++i) {
                int c   = i * 256 + tid;
                int r   = c >> 3;
                int kc8 = ((c & 7) ^ (r & 7)) << 3;
                int gr  = bm + r; gr = (gr < M) ? gr : (M - 1);
                int arow;
                if (!isCF)          arow = s + gr;            // parent rows, seg0
                else if (seg == 0)  arow = s + (gr >> 2);     // parent bcast4
                else                arow = cs + gr;           // child rows
                gload_lds16(h + ((size_t)arow << 9) + kseg0 + kc8, &As[c << 3]);
            }
        }
#pragma unroll
        for (int i = 0; i < 4; ++i) {
            int c   = i * 256 + tid;
            int r   = c >> 3;
            int kc8 = ((c & 7) ^ (r & 7)) << 3;
            gload_lds16(Bt + (size_t)(bn + r) * 1024 + k0 + kc8, &Bs[c << 3]);
        }
        __syncthreads();
        MFMA_COMPUTE(As, Bs, acc, wm, wn, lm, quad);
        __syncthreads();
    }

    const int N = isCF ? 512 : 1536;
    bf16* __restrict__ out = isCF ? CF : IOU;
    const float* b1 = isCF ? bf1 : bx1;
    const float* b2 = isCF ? bf2 : bx2;
#pragma unroll
    for (int ni = 0; ni < 4; ++ni) {
        int col = bn + wn + ni * 16 + lm;
        float bsum = b1[col] + b2[col];
#pragma unroll
        for (int mi = 0; mi < 4; ++mi) {
#pragma unroll
            for (int r = 0; r < 4; ++r) {
                int row = bm + wm + mi * 16 + quad * 4 + r;
                if (row < M)
                    out[(size_t)row * N + col] = (bf16)(acc[mi][ni][r] + bsum);
            }
        }
    }
}

// ---------------------------------------------------------------------------
// Leaf elementwise (x8 vectorized): IOU full preact -> h, cell.
__global__ void leaf_ew_kernel(const bf16* __restrict__ IOU, bf16* __restrict__ h_out,
                               float* __restrict__ cell_out, int total8)
{
    int idx = blockIdx.x * 256 + threadIdx.x;
    if (idx >= total8) return;
    int m  = idx >> 6;
    int j0 = (idx & 63) << 3;
    size_t r3 = (size_t)m * 1536 + j0;
    const bf16x8 iv = *reinterpret_cast<const bf16x8*>(&IOU[r3]);
    const bf16x8 ov = *reinterpret_cast<const bf16x8*>(&IOU[r3 + 512]);
    const bf16x8 uv = *reinterpret_cast<const bf16x8*>(&IOU[r3 + 1024]);
    bf16x8 hv;
    float cv[8];
#pragma unroll
    for (int t = 0; t < 8; ++t) {
        float i_ = sigmoidf_((float)iv[t]);
        float o_ = sigmoidf_((float)ov[t]);
        float u_ = tanhf_((float)uv[t]);
        float c = i_ * u_;
        cv[t] = c;
        hv[t] = (bf16)(o_ * tanhf_(c));
    }
    *reinterpret_cast<bf16x8*>(&h_out[(size_t)idx * 8]) = hv;
    *reinterpret_cast<float4*>(&cell_out[(size_t)idx * 8])     = *reinterpret_cast<float4*>(&cv[0]);
    *reinterpret_cast<float4*>(&cell_out[(size_t)idx * 8 + 4]) = *reinterpret_cast<float4*>(&cv[4]);
}

// Internal-node elementwise (x8): IOU (E x 1536), CF (4E x 512), cellc (4E x 512 fp32).
__global__ void internal_ew_kernel(const bf16* __restrict__ IOU, const bf16* __restrict__ CF,
                                   const float* __restrict__ cellc, bf16* __restrict__ h_out,
                                   float* __restrict__ cell_out, int total8)
{
    int idx = blockIdx.x * 256 + threadIdx.x;
    if (idx >= total8) return;
    int m  = idx >> 6;
    int j0 = (idx & 63) << 3;
    size_t r3 = (size_t)m * 1536 + j0;
    const bf16x8 iv = *reinterpret_cast<const bf16x8*>(&IOU[r3]);
    const bf16x8 ov = *reinterpret_cast<const bf16x8*>(&IOU[r3 + 512]);
    const bf16x8 uv = *reinterpret_cast<const bf16x8*>(&IOU[r3 + 1024]);
    float accv[8];
#pragma unroll
    for (int t = 0; t < 8; ++t) accv[t] = 0.f;
#pragma unroll
    for (int k = 0; k < 4; ++k) {
        size_t cr = (size_t)(4 * m + k) * 512 + j0;
        const bf16x8 fv = *reinterpret_cast<const bf16x8*>(&CF[cr]);
        const float4 c0 = *reinterpret_cast<const float4*>(&cellc[cr]);
        const float4 c1 = *reinterpret_cast<const float4*>(&cellc[cr + 4]);
        const float cc[8] = {c0.x, c0.y, c0.z, c0.w, c1.x, c1.y, c1.z, c1.w};
#pragma unroll
        for (int t = 0; t < 8; ++t) accv[t] += sigmoidf_((float)fv[t]) * cc[t];
    }
    bf16x8 hv;
    float cv[8];
#pragma unroll
    for (int t = 0; t < 8; ++t) {
        float i_ = sigmoidf_((float)iv[t]);
        float o_ = sigmoidf_((float)ov[t]);
        float u_ = tanhf_((float)uv[t]);
        float c = i_ * u_ + accv[t];
        cv[t] = c;
        hv[t] = (bf16)(o_ * tanhf_(c));
    }
    *reinterpret_cast<bf16x8*>(&h_out[(size_t)idx * 8]) = hv;
    *reinterpret_cast<float4*>(&cell_out[(size_t)idx * 8])     = *reinterpret_cast<float4*>(&cv[0]);
    *reinterpret_cast<float4*>(&cell_out[(size_t)idx * 8 + 4]) = *reinterpret_cast<float4*>(&cv[4]);
}

// ---------------------------------------------------------------------------
// tree_emb = column sum of node_emb, 3-stage parallel reduction
#define R1_BLOCKS 2048
#define R1_ROWS 43          // 2048*43 = 88064 >= 87381
__global__ void reduce1_kernel(const float* __restrict__ ne, float* __restrict__ partial)
{
    int t = threadIdx.x;
    int b = blockIdx.x;
    int r0 = b * R1_ROWS;
    int r1 = r0 + R1_ROWS; r1 = (r1 < NN) ? r1 : NN;
    float acc = 0.f;
    for (int r = r0; r < r1; ++r) acc += ne[(size_t)r * 256 + t];
    partial[(size_t)b * 256 + t] = acc;
}
__global__ void reduce2_kernel(const float* __restrict__ partial, float* __restrict__ partial2)
{
    int t = threadIdx.x;
    int b = blockIdx.x;      // 0..63
    float acc = 0.f;
    for (int i = 0; i < 32; ++i) acc += partial[(size_t)(b * 32 + i) * 256 + t];
    partial2[(size_t)b * 256 + t] = acc;
}
__global__ void reduce3_kernel(const float* __restrict__ partial2, float* __restrict__ tree)
{
    int t = threadIdx.x;
    float acc = 0.f;
    for (int i = 0; i < 64; ++i) acc += partial2[(size_t)i * 256 + t];
    tree[t] = acc;
}

// ---------------------------------------------------------------------------
extern "C" void kernel_launch(void* const* d_in, const int* in_sizes, int n_in,
                              void* d_out, int out_size, void* d_ws, size_t ws_size,
                              hipStream_t stream)
{
    const float* x      = (const float*)d_in[0];
    const float* W_in   = (const float*)d_in[8];
    const float* b_in   = (const float*)d_in[9];
    const float* W_ioux = (const float*)d_in[10];
    const float* b_ioux = (const float*)d_in[11];
    const float* W_iouh = (const float*)d_in[12];
    const float* b_iouh = (const float*)d_in[13];
    const float* W_fx   = (const float*)d_in[14];
    const float* b_fx   = (const float*)d_in[15];
    const float* W_fh   = (const float*)d_in[16];
    const float* b_fh   = (const float*)d_in[17];
    const float* W_out  = (const float*)d_in[18];
    const float* b_out  = (const float*)d_in[19];

    static const int LS[10] = {0, 1, 5, 21, 85, 341, 1365, 5461, 21845, 87381};

    char* ws = (char*)d_ws;
    size_t off = 0;
    auto take = [&](size_t bytes) -> void* {
        void* p = ws + off;
        off += (bytes + 255) & ~(size_t)255;
        return p;
    };
    bf16*  wt_in      = (bf16*) take((size_t)512 * 512 * 2);
    bf16*  wt_out     = (bf16*) take((size_t)256 * 512 * 2);
    bf16*  wt_iou_cat = (bf16*) take((size_t)2 * 1536 * 1024 * 2);
    bf16*  wt_f_cat   = (bf16*) take((size_t)2 * 512 * 1024 * 2);
    bf16*  h          = (bf16*) take((size_t)NN * 512 * 2);
    float* cell_int   = (float*)take((size_t)NINT * 512 * 4);
    float* cell_leaf  = (float*)take((size_t)8192 * 512 * 4);
    bf16*  IOU        = (bf16*) take((size_t)8192 * 1536 * 2);
    bf16*  CF         = (bf16*) take((size_t)16384 * 512 * 2);
    float* partial    = (float*)take((size_t)R1_BLOCKS * 256 * 4);
    float* partial2   = (float*)take((size_t)64 * 256 * 4);
    // x-as-bf16 staging aliases cell/IOU region (all dead during input proj)
    bf16*  xbf        = (bf16*)cell_int;

    dim3 blk(256);
    auto tgrid = [](int total) { return dim3((unsigned)((total + 255) / 256)); };

    // --- weight transpose+convert (~9 MB, one pass) ---
    tconv_kernel<<<tgrid(512 * 512), blk, 0, stream>>>(W_in, wt_in, 512, 512 * 512);
    tconv_kernel<<<tgrid(256 * 512), blk, 0, stream>>>(W_out, wt_out, 256, 256 * 512);
    for (int l = 0; l < 2; ++l) {
        tcat_kernel<<<tgrid(1536 * 1024), blk, 0, stream>>>(
            W_ioux + (size_t)l * 512 * 1536, W_iouh + (size_t)l * 512 * 1536,
            wt_iou_cat + (size_t)l * 1536 * 1024, 1536, 1536 * 1024);
        tcat_kernel<<<tgrid(512 * 1024), blk, 0, stream>>>(
            W_fx + (size_t)l * 512 * 512, W_fh + (size_t)l * 512 * 512,
            wt_f_cat + (size_t)l * 512 * 1024, 512, 512 * 1024);
    }

    auto gemm = [&](const bf16* A, const bf16* Bt, int bstride, int K,
                    float* Cf, bf16* Cb, const float* b1, const float* b2,
                    int M, int N, int relu) {
        int mt = (M + 127) / 128, nt = N / 128;
        gemm_kernel<<<dim3((unsigned)(mt * nt)), blk, 0, stream>>>(
            A, Bt, bstride, K, nt, Cf, Cb, b1, b2, M, N, relu);
    };
    auto level = [&](int s, int cs, int E, const bf16* wiou, const bf16* wf,
                     const float* bx1, const float* bx2,
                     const float* bf1, const float* bf2) {
        int iou_blocks = ((E + 127) / 128) * 12;
        int cf_blocks  = ((4 * E + 127) / 128) * 4;
        level_kernel<<<dim3((unsigned)(iou_blocks + cf_blocks)), blk, 0, stream>>>(
            h, s, cs, E, iou_blocks, wiou, wf, bx1, bx2, bf1, bf2, IOU, CF);
    };

    // --- input projection: h = relu(x @ W_in + b_in) ---
    convx_kernel<<<tgrid(NN * 128), blk, 0, stream>>>(x, xbf, NN * 128);
    gemm(xbf, wt_in, 512, 512, nullptr, h, b_in, nullptr, NN, 512, 1);

    for (int l = 0; l < 2; ++l) {
        const bf16* wiou = wt_iou_cat + (size_t)l * 1536 * 1024;
        const bf16* wf   = wt_f_cat + (size_t)l * 512 * 1024;
        const float* bx1 = b_ioux + (size_t)l * 1536;
        const float* bx2 = b_iouh + (size_t)l * 1536;
        const float* bf1 = b_fx + (size_t)l * 512;
        const float* bf2 = b_fh + (size_t)l * 512;

        // leaves + level-7 parents, pipelined in 8 chunks
        for (int c = 0; c < 8; ++c) {
            int lr0 = LEAF_START + 8192 * c;   // leaf rows [lr0, lr0+8192)
            gemm(h + (size_t)lr0 * 512, wiou, 1024, 512,
                 nullptr, IOU, bx1, bx2, 8192, 1536, 0);
            leaf_ew_kernel<<<tgrid(8192 * 64), blk, 0, stream>>>(
                IOU, h + (size_t)lr0 * 512, cell_leaf, 8192 * 64);
            int p0  = 5461 + 2048 * c;         // level-7 parents
            int cs0 = 4 * p0 + 1;              // == lr0
            level(p0, cs0, 2048, wiou, wf, bx1, bx2, bf1, bf2);
            internal_ew_kernel<<<tgrid(2048 * 64), blk, 0, stream>>>(
                IOU, CF, cell_leaf, h + (size_t)p0 * 512,
                cell_int + (size_t)p0 * 512, 2048 * 64);
        }
        // levels 6..0
        for (int d = 6; d >= 0; --d) {
            int s  = LS[d];
            int E  = LS[d + 1] - LS[d];
            int cs = 4 * s + 1;                // == LS[d+1]
            level(s, cs, E, wiou, wf, bx1, bx2, bf1, bf2);
            internal_ew_kernel<<<tgrid(E * 64), blk, 0, stream>>>(
                IOU, CF, cell_int + (size_t)cs * 512, h + (size_t)s * 512,
                cell_int + (size_t)s * 512, E * 64);
        }
    }

    // --- output projection + tree reduction ---
    float* node_emb = (float*)d_out;
    gemm(h, wt_out, 512, 512, node_emb, nullptr, b_out, nullptr, NN, 256, 0);
    reduce1_kernel<<<dim3(R1_BLOCKS), blk, 0, stream>>>(node_emb, partial);
    reduce2_kernel<<<dim3(64), blk, 0, stream>>>(partial, partial2);
    reduce3_kernel<<<dim3(1), blk, 0, stream>>>(partial2, node_emb + (size_t)NN * 256);
}